// Round 1
// baseline (421.866 us; speedup 1.0000x reference)
//
#include <hip/hip_runtime.h>
#include <hip/hip_bf16.h>

#define B_SZ 1024
#define C_SZ 100
#define D_SZ 768

#define BN 64                 // b-rows per workgroup
#define BK 32                 // e-contraction step per staging round
#define NBT (B_SZ / BN)       // 16 b-tiles
#define XS_STRIDE (D_SZ + 8)  // 776 ushorts (pad -> 2-way-free banks)
#define AS_STRIDE (BK + 8)    // 40 ushorts
#define NTHREADS 512
#define NWAVES 8
#define MF 6                  // 16-row d-fragments per wave (wave d-tile = 96)
#define NF 4                  // 16-col b-fragments per wave (64 b)

typedef float f32x4 __attribute__((ext_vector_type(4)));
typedef short short8 __attribute__((ext_vector_type(8)));

__device__ __forceinline__ ushort f2bf(float f) {
    union { __hip_bfloat16 b; ushort u; } cv;
    cv.b = __float2bfloat16(f);
    return cv.u;
}
__device__ __forceinline__ float bf2f(ushort u) {
    union { __hip_bfloat16 b; ushort us; } cv;
    cv.us = u;
    return __bfloat162float(cv.b);
}

__global__ __launch_bounds__(NTHREADS, 2) void fecam_scores(
        const float* __restrict__ raw, const float* __restrict__ mean,
        const float* __restrict__ inv, const float* __restrict__ diag,
        float* __restrict__ out) {
    __shared__ ushort xs[BN * XS_STRIDE];     // 99,328 B  x tile, bf16
    __shared__ ushort as_[D_SZ * AS_STRIDE];  // 61,440 B  A k-slab, bf16
    __shared__ float red[NWAVES][BN];         //  2,048 B

    const int tid = (int)threadIdx.x;
    const int c  = (int)blockIdx.x / NBT;          // class-major: consecutive
    const int b0 = ((int)blockIdx.x % NBT) * BN;   // blocks share A_c in L2/L3

    // ---- stage X = (raw - mean) / diag as bf16 into LDS (once) ----
    for (int idx = tid; idx < BN * (D_SZ / 4); idx += NTHREADS) {
        const int row = idx / (D_SZ / 4);
        const int col = (idx % (D_SZ / 4)) * 4;
        const f32x4 rv = *(const f32x4*)(raw + (size_t)(b0 + row) * D_SZ + col);
        const f32x4 mv = *(const f32x4*)(mean + (size_t)c * D_SZ + col);
        const f32x4 dv = *(const f32x4*)(diag + (size_t)c * D_SZ + col);
        ushort4 p;
        p.x = f2bf((rv.x - mv.x) / dv.x);
        p.y = f2bf((rv.y - mv.y) / dv.y);
        p.z = f2bf((rv.z - mv.z) / dv.z);
        p.w = f2bf((rv.w - mv.w) / dv.w);
        *(ushort4*)(xs + row * XS_STRIDE + col) = p;
    }

    const int lane = tid & 63;
    const int wid  = tid >> 6;   // 0..7 : wave owns d-rows [wid*96, wid*96+96)
    const int l15  = lane & 15;
    const int l4   = lane >> 4;  // 0..3

    f32x4 tacc[MF][NF] = {};     // temp' fragments, f32 accum

    const float* Ab = inv + (size_t)c * D_SZ * D_SZ;

    for (int kt = 0; kt < D_SZ / BK; ++kt) {   // 24 k-slabs over e
        const int k0 = kt * BK;
        __syncthreads();
        // stage A[0:768][k0:k0+32] -> bf16 LDS (coalesced, linear writes)
        #pragma unroll
        for (int i = 0; i < (D_SZ * (BK / 4)) / NTHREADS; ++i) {   // 12
            const int idx = tid + i * NTHREADS;
            const int row = idx >> 3;
            const int col = (idx & 7) * 4;
            const f32x4 av = *(const f32x4*)(Ab + (size_t)row * D_SZ + k0 + col);
            ushort4 p;
            p.x = f2bf(av.x); p.y = f2bf(av.y); p.z = f2bf(av.z); p.w = f2bf(av.w);
            *(ushort4*)(as_ + row * AS_STRIDE + col) = p;
        }
        __syncthreads();
        // B-fragments: Bfrag[k=e][n=b] = x[b][e]  (k-contiguous in xs rows)
        short8 bf[NF];
        #pragma unroll
        for (int nf = 0; nf < NF; ++nf)
            bf[nf] = *(const short8*)(xs + (nf * 16 + l15) * XS_STRIDE + k0 + l4 * 8);
        // A-fragments: Afrag[m=d][k=e] = A[d][e]  (k-contiguous in as_ rows)
        #pragma unroll
        for (int mf = 0; mf < MF; ++mf) {
            const short8 af = *(const short8*)(as_ + (wid * 96 + mf * 16 + l15) * AS_STRIDE + l4 * 8);
            #pragma unroll
            for (int nf = 0; nf < NF; ++nf)
                tacc[mf][nf] = __builtin_amdgcn_mfma_f32_16x16x32_bf16(af, bf[nf], tacc[mf][nf], 0, 0, 0);
        }
    }

    // ---- epilogue: acc_b += temp'[d][b] * x[b][d] ----
    // D layout (16x16x32): col = lane&15 (=b), row = (lane>>4)*4 + j (=d)
    float acc[NF] = {0.f, 0.f, 0.f, 0.f};
    #pragma unroll
    for (int mf = 0; mf < MF; ++mf) {
        #pragma unroll
        for (int j = 0; j < 4; ++j) {
            const int dl = wid * 96 + mf * 16 + l4 * 4 + j;
            #pragma unroll
            for (int nf = 0; nf < NF; ++nf) {
                const float xv = bf2f(xs[(nf * 16 + l15) * XS_STRIDE + dl]);
                acc[nf] += tacc[mf][nf][j] * xv;
            }
        }
    }
    // reduce over the 4 lane-groups holding the same b (cols)
    #pragma unroll
    for (int nf = 0; nf < NF; ++nf) {
        acc[nf] += __shfl_xor(acc[nf], 16);
        acc[nf] += __shfl_xor(acc[nf], 32);
    }
    __syncthreads();
    if (lane < 16) {
        #pragma unroll
        for (int nf = 0; nf < NF; ++nf) red[wid][nf * 16 + l15] = acc[nf];
    }
    __syncthreads();
    if (tid < BN) {
        float t = 0.f;
        #pragma unroll
        for (int w = 0; w < NWAVES; ++w) t += red[w][tid];
        out[(size_t)(b0 + tid) * C_SZ + c] = -t;
    }
}

extern "C" void kernel_launch(void* const* d_in, const int* in_sizes, int n_in,
                              void* d_out, int out_size, void* d_ws, size_t ws_size,
                              hipStream_t stream) {
    const float* raw  = (const float*)d_in[0];
    const float* mean = (const float*)d_in[1];
    const float* inv  = (const float*)d_in[2];
    const float* diag = (const float*)d_in[3];
    float* out = (float*)d_out;
    dim3 grid(C_SZ * NBT);
    fecam_scores<<<grid, NTHREADS, 0, stream>>>(raw, mean, inv, diag, out);
}

// Round 2
// 394.027 us; speedup vs baseline: 1.0707x; 1.0707x over previous
//
#include <hip/hip_runtime.h>
#include <hip/hip_bf16.h>

#define B_SZ 1024
#define C_SZ 100
#define D_SZ 768

#define BN 128                // b-rows per workgroup
#define BK 32                 // e-contraction slab
#define NBT (B_SZ / BN)       // 8
#define NKT (D_SZ / BK)       // 24
#define NTHREADS 512
#define NWAVES 8
#define MF 6                  // wave owns 96 d-rows = 6 x 16
#define NF 8                  // 128 b-cols = 8 x 16

#define XS_STRIDE 40          // ushorts (32 + 8 pad)
#define XS_HALF (BN * XS_STRIDE)     // 5120 ushorts
#define AS_HALF (D_SZ * BK)          // 24576 ushorts = 48KB, linear (gload_lds)
#define EP_STRIDE 20
#define EP_PER_WAVE (BN * EP_STRIDE) // 2560 ushorts

typedef float f32x4 __attribute__((ext_vector_type(4)));
typedef short short8 __attribute__((ext_vector_type(8)));

__device__ __forceinline__ ushort f2bf(float f) {
    union { __hip_bfloat16 b; ushort u; } cv; cv.b = __float2bfloat16(f); return cv.u;
}
__device__ __forceinline__ float bf2f(ushort u) {
    union { __hip_bfloat16 b; ushort us; } cv; cv.us = u; return __bfloat162float(cv.b);
}
__device__ __forceinline__ void gload_lds16(const void* g, void* l) {
    __builtin_amdgcn_global_load_lds((const __attribute__((address_space(1))) void*)g,
                                     (__attribute__((address_space(3))) void*)l, 16, 0, 0);
}

// ---- prepass: inv f32 -> bf16 in ws ----
__global__ __launch_bounds__(256) void conv_a_bf16(const float* __restrict__ inv,
                                                   ushort* __restrict__ ws) {
    const size_t n8 = (size_t)C_SZ * D_SZ * D_SZ / 8;
    for (size_t i = (size_t)blockIdx.x * 256 + threadIdx.x; i < n8;
         i += (size_t)gridDim.x * 256) {
        const f32x4 v0 = *(const f32x4*)(inv + i * 8);
        const f32x4 v1 = *(const f32x4*)(inv + i * 8 + 4);
        short8 p;
        p[0]=(short)f2bf(v0.x); p[1]=(short)f2bf(v0.y); p[2]=(short)f2bf(v0.z); p[3]=(short)f2bf(v0.w);
        p[4]=(short)f2bf(v1.x); p[5]=(short)f2bf(v1.y); p[6]=(short)f2bf(v1.z); p[7]=(short)f2bf(v1.w);
        *(short8*)(ws + i * 8) = p;
    }
}

// stage X slab [BN][BK] = (raw-mean)/diag as bf16 -> padded LDS
__device__ __forceinline__ void stage_x(ushort* dst, const float* raw, const float* mean,
                                        const float* diag, int c, int b0, int e0, int tid) {
    #pragma unroll
    for (int i = 0; i < (BN * (BK / 4)) / NTHREADS; ++i) {   // 2
        const int chunk = tid + i * NTHREADS;
        const int row = chunk >> 3;
        const int cc  = chunk & 7;
        const int e = e0 + cc * 4;
        const f32x4 rv = *(const f32x4*)(raw + (size_t)(b0 + row) * D_SZ + e);
        const f32x4 mv = *(const f32x4*)(mean + (size_t)c * D_SZ + e);
        const f32x4 dv = *(const f32x4*)(diag + (size_t)c * D_SZ + e);
        ushort4 p;
        p.x = f2bf((rv.x - mv.x) / dv.x);
        p.y = f2bf((rv.y - mv.y) / dv.y);
        p.z = f2bf((rv.z - mv.z) / dv.z);
        p.w = f2bf((rv.w - mv.w) / dv.w);
        *(ushort4*)(dst + row * XS_STRIDE + cc * 4) = p;
    }
}

// stage A slab [768][BK] bf16 -> linear LDS, XOR-swizzled via SOURCE address (rule 21)
template <int AMODE>
__device__ __forceinline__ void stage_a(ushort* dst, const ushort* Abf, const float* Af,
                                        int e0, int tid) {
    #pragma unroll
    for (int i = 0; i < (D_SZ * (BK / 8)) / NTHREADS; ++i) {   // 6
        const int s = tid + i * NTHREADS;        // 16B chunk slot
        const int r = s >> 2;                    // A row (d)
        const int qg = (s & 3) ^ (r & 3);        // swizzled source chunk
        if constexpr (AMODE == 1) {
            gload_lds16(Abf + (size_t)r * D_SZ + e0 + qg * 8, dst + (size_t)s * 8);
        } else {
            const float* gp = Af + (size_t)r * D_SZ + e0 + qg * 8;
            const f32x4 a0 = *(const f32x4*)gp;
            const f32x4 a1 = *(const f32x4*)(gp + 4);
            short8 p;
            p[0]=(short)f2bf(a0.x); p[1]=(short)f2bf(a0.y); p[2]=(short)f2bf(a0.z); p[3]=(short)f2bf(a0.w);
            p[4]=(short)f2bf(a1.x); p[5]=(short)f2bf(a1.y); p[6]=(short)f2bf(a1.z); p[7]=(short)f2bf(a1.w);
            *(short8*)(dst + (size_t)s * 8) = p;
        }
    }
}

template <int AMODE>
__global__ __launch_bounds__(NTHREADS, 2) void fecam_scores(
        const float* __restrict__ raw, const float* __restrict__ mean,
        const float* __restrict__ inv, const float* __restrict__ diag,
        const ushort* __restrict__ wsA, float* __restrict__ out) {
    __shared__ __align__(16) ushort aLds[2 * AS_HALF];   // 98,304 B
    __shared__ __align__(16) ushort xLds[2 * XS_HALF];   // 20,480 B
    __shared__ float red[NWAVES * BN];                   //  4,096 B

    const int tid = (int)threadIdx.x;
    const int bx  = (int)blockIdx.x;
    const int c   = bx % C_SZ;            // bt-major: class c's 8 tiles land on 2 XCDs
    const int b0  = (bx / C_SZ) * BN;

    const int lane = tid & 63;
    const int wid  = tid >> 6;
    const int l15  = lane & 15;
    const int l4   = lane >> 4;

    const ushort* Abf = wsA + (size_t)c * D_SZ * D_SZ;
    const float*  Af  = inv + (size_t)c * D_SZ * D_SZ;

    // prologue: stage slab 0
    stage_a<AMODE>(aLds, Abf, Af, 0, tid);
    stage_x(xLds, raw, mean, diag, c, b0, 0, tid);
    __syncthreads();

    f32x4 tacc[MF][NF] = {};   // temp'[d,b] fragments, f32

    for (int kt = 0; kt < NKT; ++kt) {
        const int cur = kt & 1;
        if (kt + 1 < NKT) {
            stage_a<AMODE>(aLds + (cur ^ 1) * AS_HALF, Abf, Af, (kt + 1) * BK, tid);
            stage_x(xLds + (cur ^ 1) * XS_HALF, raw, mean, diag, c, b0, (kt + 1) * BK, tid);
        }
        const ushort* xc = xLds + cur * XS_HALF;
        const ushort* ac = aLds + cur * AS_HALF;
        short8 bfr[NF];
        #pragma unroll
        for (int nf = 0; nf < NF; ++nf)
            bfr[nf] = *(const short8*)(xc + (nf * 16 + l15) * XS_STRIDE + l4 * 8);
        #pragma unroll
        for (int mf = 0; mf < MF; ++mf) {
            const int r = wid * 96 + mf * 16 + l15;
            const int slot = (r << 2) | (l4 ^ (r & 3));      // read-side XOR (matches source swz)
            const short8 af = *(const short8*)(ac + slot * 8);
            #pragma unroll
            for (int nf = 0; nf < NF; ++nf)
                tacc[mf][nf] = __builtin_amdgcn_mfma_f32_16x16x32_bf16(af, bfr[nf], tacc[mf][nf], 0, 0, 0);
        }
        __syncthreads();
    }

    // ---- epilogue: dist[b] += temp'[d,b] * x[b,d], wave-private LDS staging ----
    // C/D layout (validated R1): col(b)=l15, row(d)=l4*4+j
    ushort* wbuf = aLds + wid * EP_PER_WAVE;   // aliases dead A region, wave-private
    float accb[NF] = {};
    #pragma unroll
    for (int mf = 0; mf < MF; ++mf) {
        const int d0 = wid * 96 + mf * 16;
        #pragma unroll
        for (int i = 0; i < 8; ++i) {
            const int chunk = lane + (i << 6);   // 0..511
            const int row = chunk >> 2;
            const int cc  = chunk & 3;
            const int d = d0 + cc * 4;
            const f32x4 rv = *(const f32x4*)(raw + (size_t)(b0 + row) * D_SZ + d);
            const f32x4 mv = *(const f32x4*)(mean + (size_t)c * D_SZ + d);
            const f32x4 dv = *(const f32x4*)(diag + (size_t)c * D_SZ + d);
            ushort4 p;
            p.x = f2bf((rv.x - mv.x) / dv.x);
            p.y = f2bf((rv.y - mv.y) / dv.y);
            p.z = f2bf((rv.z - mv.z) / dv.z);
            p.w = f2bf((rv.w - mv.w) / dv.w);
            *(ushort4*)(wbuf + row * EP_STRIDE + cc * 4) = p;
        }
        // wave-private buffer: compiler inserts lgkmcnt between ds_write/ds_read
        #pragma unroll
        for (int nf = 0; nf < NF; ++nf) {
            #pragma unroll
            for (int j = 0; j < 4; ++j) {
                const float xv = bf2f(wbuf[(nf * 16 + l15) * EP_STRIDE + l4 * 4 + j]);
                accb[nf] += tacc[mf][nf][j] * xv;
            }
        }
    }

    #pragma unroll
    for (int nf = 0; nf < NF; ++nf) {
        accb[nf] += __shfl_xor(accb[nf], 16);
        accb[nf] += __shfl_xor(accb[nf], 32);
    }
    if (lane < 16) {
        #pragma unroll
        for (int nf = 0; nf < NF; ++nf) red[wid * BN + nf * 16 + l15] = accb[nf];
    }
    __syncthreads();
    if (tid < BN) {
        float t = 0.f;
        #pragma unroll
        for (int w = 0; w < NWAVES; ++w) t += red[w * BN + tid];
        out[(size_t)(b0 + tid) * C_SZ + c] = -t;
    }
}

extern "C" void kernel_launch(void* const* d_in, const int* in_sizes, int n_in,
                              void* d_out, int out_size, void* d_ws, size_t ws_size,
                              hipStream_t stream) {
    const float* raw  = (const float*)d_in[0];
    const float* mean = (const float*)d_in[1];
    const float* inv  = (const float*)d_in[2];
    const float* diag = (const float*)d_in[3];
    float* out = (float*)d_out;
    const size_t need = (size_t)C_SZ * D_SZ * D_SZ * sizeof(ushort);
    dim3 grid(C_SZ * NBT);
    if (ws_size >= need) {
        ushort* ws = (ushort*)d_ws;
        conv_a_bf16<<<2048, 256, 0, stream>>>(inv, ws);
        fecam_scores<1><<<grid, NTHREADS, 0, stream>>>(raw, mean, inv, diag, ws, out);
    } else {
        fecam_scores<0><<<grid, NTHREADS, 0, stream>>>(raw, mean, inv, diag, nullptr, out);
    }
}

// Round 3
// 374.129 us; speedup vs baseline: 1.1276x; 1.0532x over previous
//
#include <hip/hip_runtime.h>
#include <hip/hip_bf16.h>

#define B_SZ 1024
#define C_SZ 100
#define D_SZ 768

#define BN 128                // b-rows per workgroup
#define BK 32                 // e-contraction slab
#define NKT (D_SZ / BK)       // 24
#define NTHREADS 512
#define NWAVES 8
#define MF 6                  // wave owns 96 d-rows = 6 x 16
#define NF 8                  // 128 b-cols = 8 x 16

#define XS_STRIDE 40          // ushorts (32 + 8 pad) -> 80B row stride, 2-way free
#define XS_HALF (BN * XS_STRIDE)     // 5120 ushorts
#define AS_HALF (D_SZ * BK)          // 24576 ushorts = 48KB, linear (gload_lds)
#define EP_STRIDE 20
#define EP_PER_WAVE (BN * EP_STRIDE) // 2560 ushorts

typedef float f32x4 __attribute__((ext_vector_type(4)));
typedef short short8 __attribute__((ext_vector_type(8)));

__device__ __forceinline__ ushort f2bf(float f) {
    union { __hip_bfloat16 b; ushort u; } cv; cv.b = __float2bfloat16(f); return cv.u;
}
__device__ __forceinline__ float bf2f(ushort u) {
    union { __hip_bfloat16 b; ushort us; } cv; cv.us = u; return __bfloat162float(cv.b);
}
__device__ __forceinline__ void gload_lds16(const void* g, void* l) {
    __builtin_amdgcn_global_load_lds((const __attribute__((address_space(1))) void*)g,
                                     (__attribute__((address_space(3))) void*)l, 16, 0, 0);
}

// ---- prepass: inv f32 -> bf16 in ws ----
__global__ __launch_bounds__(256) void conv_a_bf16(const float* __restrict__ inv,
                                                   ushort* __restrict__ ws) {
    const size_t n8 = (size_t)C_SZ * D_SZ * D_SZ / 8;
    for (size_t i = (size_t)blockIdx.x * 256 + threadIdx.x; i < n8;
         i += (size_t)gridDim.x * 256) {
        const f32x4 v0 = *(const f32x4*)(inv + i * 8);
        const f32x4 v1 = *(const f32x4*)(inv + i * 8 + 4);
        short8 p;
        p[0]=(short)f2bf(v0.x); p[1]=(short)f2bf(v0.y); p[2]=(short)f2bf(v0.z); p[3]=(short)f2bf(v0.w);
        p[4]=(short)f2bf(v1.x); p[5]=(short)f2bf(v1.y); p[6]=(short)f2bf(v1.z); p[7]=(short)f2bf(v1.w);
        *(short8*)(ws + i * 8) = p;
    }
}

// stage X slab [BN][BK] = (raw-mean)/diag as bf16 -> padded LDS
__device__ __forceinline__ void stage_x(ushort* dst, const float* raw, const float* mean,
                                        const float* diag, int c, int b0, int e0, int tid) {
    #pragma unroll
    for (int i = 0; i < (BN * (BK / 4)) / NTHREADS; ++i) {   // 2
        const int chunk = tid + i * NTHREADS;
        const int row = chunk >> 3;
        const int cc  = chunk & 7;
        const int e = e0 + cc * 4;
        const f32x4 rv = *(const f32x4*)(raw + (size_t)(b0 + row) * D_SZ + e);
        const f32x4 mv = *(const f32x4*)(mean + (size_t)c * D_SZ + e);
        const f32x4 dv = *(const f32x4*)(diag + (size_t)c * D_SZ + e);
        ushort4 p;
        p.x = f2bf((rv.x - mv.x) / dv.x);
        p.y = f2bf((rv.y - mv.y) / dv.y);
        p.z = f2bf((rv.z - mv.z) / dv.z);
        p.w = f2bf((rv.w - mv.w) / dv.w);
        *(ushort4*)(dst + row * XS_STRIDE + cc * 4) = p;
    }
}

// stage A slab [768][BK] bf16 -> linear LDS.
// Source-side XOR swizzle (rule 21): conflict axis is the ROW (64B apart in the
// slab -> bank period 8 rows with b128). qg = chunk ^ ((r>>1)&3) spreads 8
// consecutive rows over 8 distinct bank-quads; 16 rows -> free 2-way.
template <int AMODE>
__device__ __forceinline__ void stage_a(ushort* dst, const ushort* Abf, const float* Af,
                                        int e0, int tid) {
    #pragma unroll
    for (int i = 0; i < (D_SZ * (BK / 8)) / NTHREADS; ++i) {   // 6
        const int s = tid + i * NTHREADS;        // 16B chunk slot
        const int r = s >> 2;                    // A row (d)
        const int qg = (s & 3) ^ ((r >> 1) & 3); // swizzled source chunk
        if constexpr (AMODE == 1) {
            gload_lds16(Abf + (size_t)r * D_SZ + e0 + qg * 8, dst + (size_t)s * 8);
        } else {
            const float* gp = Af + (size_t)r * D_SZ + e0 + qg * 8;
            const f32x4 a0 = *(const f32x4*)gp;
            const f32x4 a1 = *(const f32x4*)(gp + 4);
            short8 p;
            p[0]=(short)f2bf(a0.x); p[1]=(short)f2bf(a0.y); p[2]=(short)f2bf(a0.z); p[3]=(short)f2bf(a0.w);
            p[4]=(short)f2bf(a1.x); p[5]=(short)f2bf(a1.y); p[6]=(short)f2bf(a1.z); p[7]=(short)f2bf(a1.w);
            *(short8*)(dst + (size_t)s * 8) = p;
        }
    }
}

template <int AMODE>
__global__ __launch_bounds__(NTHREADS, 2) void fecam_scores(
        const float* __restrict__ raw, const float* __restrict__ mean,
        const float* __restrict__ inv, const float* __restrict__ diag,
        const ushort* __restrict__ wsA, float* __restrict__ out) {
    __shared__ __align__(16) ushort aLds[2 * AS_HALF];   // 98,304 B
    __shared__ __align__(16) ushort xLds[2 * XS_HALF];   // 20,480 B
    __shared__ float red[NWAVES * BN];                   //  4,096 B

    const int tid = (int)threadIdx.x;
    const int bx  = (int)blockIdx.x;

    // XCD-pinned class grouping: xcd = bx & 7 (round-robin dispatch, m09).
    // Each XCD owns 12-13 whole classes; the 8 b-tiles of a class occupy
    // consecutive slots -> co-resident on the same XCD -> A_c slab L2-hits.
    const int x = bx & 7;
    const int j = bx >> 3;
    const int nCls  = (x < 4) ? 13 : 12;
    const int baseC = (x < 4) ? x * 13 : 52 + (x - 4) * 12;
    const int ci = j >> 3;
    if (ci >= nCls) return;
    const int c  = baseC + ci;
    const int b0 = (j & 7) * BN;

    const int lane = tid & 63;
    const int wid  = tid >> 6;
    const int l15  = lane & 15;
    const int l4   = lane >> 4;

    const ushort* Abf = wsA + (size_t)c * D_SZ * D_SZ;
    const float*  Af  = inv + (size_t)c * D_SZ * D_SZ;

    // prologue: stage slab 0
    stage_a<AMODE>(aLds, Abf, Af, 0, tid);
    stage_x(xLds, raw, mean, diag, c, b0, 0, tid);
    __syncthreads();

    f32x4 tacc[MF][NF] = {};   // temp'[d,b] fragments, f32

    for (int kt = 0; kt < NKT; ++kt) {
        const int cur = kt & 1;
        if (kt + 1 < NKT) {
            stage_a<AMODE>(aLds + (cur ^ 1) * AS_HALF, Abf, Af, (kt + 1) * BK, tid);
            stage_x(xLds + (cur ^ 1) * XS_HALF, raw, mean, diag, c, b0, (kt + 1) * BK, tid);
        }
        const ushort* xc = xLds + cur * XS_HALF;
        const ushort* ac = aLds + cur * AS_HALF;
        short8 bfr[NF];
        #pragma unroll
        for (int nf = 0; nf < NF; ++nf)
            bfr[nf] = *(const short8*)(xc + (nf * 16 + l15) * XS_STRIDE + l4 * 8);
        #pragma unroll
        for (int mf = 0; mf < MF; ++mf) {
            const int r = wid * 96 + mf * 16 + l15;
            const int slot = (r << 2) | (l4 ^ ((r >> 1) & 3));  // matches source swz
            const short8 af = *(const short8*)(ac + slot * 8);
            #pragma unroll
            for (int nf = 0; nf < NF; ++nf)
                tacc[mf][nf] = __builtin_amdgcn_mfma_f32_16x16x32_bf16(af, bfr[nf], tacc[mf][nf], 0, 0, 0);
        }
        __syncthreads();
    }

    // ---- epilogue: dist[b] += temp'[d,b] * x[b,d], wave-private LDS staging ----
    // C/D layout (validated R1): col(b)=l15, row(d)=l4*4+j
    ushort* wbuf = aLds + wid * EP_PER_WAVE;   // aliases dead A region, wave-private
    float accb[NF] = {};
    #pragma unroll
    for (int mf = 0; mf < MF; ++mf) {
        const int d0 = wid * 96 + mf * 16;
        #pragma unroll
        for (int i = 0; i < 8; ++i) {
            const int chunk = lane + (i << 6);   // 0..511
            const int row = chunk >> 2;
            const int cc  = chunk & 3;
            const int d = d0 + cc * 4;
            const f32x4 rv = *(const f32x4*)(raw + (size_t)(b0 + row) * D_SZ + d);
            const f32x4 mv = *(const f32x4*)(mean + (size_t)c * D_SZ + d);
            const f32x4 dv = *(const f32x4*)(diag + (size_t)c * D_SZ + d);
            ushort4 p;
            p.x = f2bf((rv.x - mv.x) / dv.x);
            p.y = f2bf((rv.y - mv.y) / dv.y);
            p.z = f2bf((rv.z - mv.z) / dv.z);
            p.w = f2bf((rv.w - mv.w) / dv.w);
            *(ushort4*)(wbuf + row * EP_STRIDE + cc * 4) = p;
        }
        // wave-private buffer: compiler inserts lgkmcnt between ds_write/ds_read
        #pragma unroll
        for (int nf = 0; nf < NF; ++nf) {
            #pragma unroll
            for (int jj = 0; jj < 4; ++jj) {
                const float xv = bf2f(wbuf[(nf * 16 + l15) * EP_STRIDE + l4 * 4 + jj]);
                accb[nf] += tacc[mf][nf][jj] * xv;
            }
        }
    }

    #pragma unroll
    for (int nf = 0; nf < NF; ++nf) {
        accb[nf] += __shfl_xor(accb[nf], 16);
        accb[nf] += __shfl_xor(accb[nf], 32);
    }
    if (lane < 16) {
        #pragma unroll
        for (int nf = 0; nf < NF; ++nf) red[wid * BN + nf * 16 + l15] = accb[nf];
    }
    __syncthreads();
    if (tid < BN) {
        float t = 0.f;
        #pragma unroll
        for (int w = 0; w < NWAVES; ++w) t += red[w * BN + tid];
        out[(size_t)(b0 + tid) * C_SZ + c] = -t;
    }
}

extern "C" void kernel_launch(void* const* d_in, const int* in_sizes, int n_in,
                              void* d_out, int out_size, void* d_ws, size_t ws_size,
                              hipStream_t stream) {
    const float* raw  = (const float*)d_in[0];
    const float* mean = (const float*)d_in[1];
    const float* inv  = (const float*)d_in[2];
    const float* diag = (const float*)d_in[3];
    float* out = (float*)d_out;
    const size_t need = (size_t)C_SZ * D_SZ * D_SZ * sizeof(ushort);
    dim3 grid(104 * 8);   // 8 XCD groups x 104 slots (13 classes x 8 tiles max)
    if (ws_size >= need) {
        ushort* ws = (ushort*)d_ws;
        conv_a_bf16<<<2048, 256, 0, stream>>>(inv, ws);
        fecam_scores<1><<<grid, NTHREADS, 0, stream>>>(raw, mean, inv, diag, ws, out);
    } else {
        fecam_scores<0><<<grid, NTHREADS, 0, stream>>>(raw, mean, inv, diag, nullptr, out);
    }
}